// Round 16
// baseline (566.749 us; speedup 1.0000x reference)
//
#include <hip/hip_runtime.h>
#include <math.h>

constexpr int Bn = 4, Cc = 128, On = 128, Hh = 160, Ww = 160, Kk = 9;
constexpr int HW = Hh * Ww;          // 25600

typedef __attribute__((ext_vector_type(8))) short s16x8;
typedef __attribute__((ext_vector_type(4))) float f32x4;

__device__ inline float bf2f(short s) {
    union { float f; unsigned u; } v;
    v.u = ((unsigned)(unsigned short)s) << 16;
    return v.f;
}
__device__ inline short f2bf(float f) {
    union { float f; unsigned u; } v;
    v.f = f;
    unsigned r = v.u + 0x7fffu + ((v.u >> 16) & 1u);   // RNE
    return (short)(r >> 16);
}

// ---------------------------------------------------------------------------
// Kernel A1: x (NCHW f32) -> xT (NHWC bf16 hi) + xLo (NHWC bf16 lo).
// ---------------------------------------------------------------------------
__global__ __launch_bounds__(256) void to_nhwc(const float* __restrict__ x,
                                               short* __restrict__ xT,
                                               short* __restrict__ xLo) {
    __shared__ float tile[128][65];
    const int t = threadIdx.x;
    const int p0 = blockIdx.x * 64;
    const int b = blockIdx.y;
#pragma unroll
    for (int i = 0; i < 32; ++i) {
        int c = i * 4 + (t >> 6);
        tile[c][t & 63] = x[((size_t)b * Cc + c) * HW + p0 + (t & 63)];
    }
    __syncthreads();
    const int px = t >> 2, cq = t & 3;
    short* dsth = xT  + ((size_t)(b * HW) + p0 + px) * Cc;
    short* dstl = xLo + ((size_t)(b * HW) + p0 + px) * Cc;
#pragma unroll
    for (int j = 0; j < 8; ++j) {
        int c0 = cq * 4 + j * 16;
        short4 vh, vl;
        float f0 = tile[c0 + 0][px], f1 = tile[c0 + 1][px];
        float f2 = tile[c0 + 2][px], f3 = tile[c0 + 3][px];
        vh.x = f2bf(f0); vh.y = f2bf(f1); vh.z = f2bf(f2); vh.w = f2bf(f3);
        vl.x = f2bf(f0 - bf2f(vh.x));
        vl.y = f2bf(f1 - bf2f(vh.y));
        vl.z = f2bf(f2 - bf2f(vh.z));
        vl.w = f2bf(f3 - bf2f(vh.w));
        *(short4*)(dsth + c0) = vh;
        *(short4*)(dstl + c0) = vl;
    }
}

// ---------------------------------------------------------------------------
// Kernel A2: wt (O,C,3,3) f32 -> wb[k][o][c] bf16
// ---------------------------------------------------------------------------
__global__ void prep_w(const float* __restrict__ wt, short* __restrict__ wb) {
    int idx = blockIdx.x * 256 + threadIdx.x;     // K*O*C = 147456
    if (idx >= Kk * On * Cc) return;
    int c = idx & 127;
    int o = (idx >> 7) & 127;
    int k = idx >> 14;
    wb[idx] = f2bf(wt[(o * Cc + c) * 9 + k]);
}

// ---------------------------------------------------------------------------
// Kernel A3: offset/mask weights -> wofm_{hi,lo}[k][ch32][c].
// ---------------------------------------------------------------------------
__global__ void prep_wofm(const float* __restrict__ w_off,
                          const float* __restrict__ w_mask,
                          short* __restrict__ wh, short* __restrict__ wl) {
    int idx = blockIdx.x * 256 + threadIdx.x;     // 9*32*128 = 36864
    if (idx >= Kk * 32 * Cc) return;
    int c = idx & 127;
    int ch = (idx >> 7) & 31;
    int k = idx >> 12;
    float v = 0.f;
    if (ch < 18)      v = w_off[(ch * Cc + c) * 9 + k];
    else if (ch < 27) v = w_mask[((ch - 18) * Cc + c) * 9 + k];
    short hi = f2bf(v);
    wh[idx] = hi;
    wl[idx] = f2bf(v - bf2f(hi));
}

// ---------------------------------------------------------------------------
// Kernel B: offset/mask conv via MFMA, hi/lo split (r13 version, unchanged).
// ---------------------------------------------------------------------------
__global__ __launch_bounds__(256) void offmask_mfma(
    const short* __restrict__ xT, const short* __restrict__ xLo,
    const short* __restrict__ wh, const short* __restrict__ wl,
    const float* __restrict__ b_off, const float* __restrict__ b_mask,
    float* __restrict__ dy_o, float* __restrict__ dx_o, float* __restrict__ mk_o)
{
    __shared__ short a_hi[6][2304];
    __shared__ short a_lo[6][2304];

    const int g = blockIdx.x;
    const int orig = (g & 7) * 200 + (g >> 3);
    const int b  = orig / 400;
    const int rem = orig % 400;
    const int h0 = (rem / 10) * 4;
    const int w0 = (rem % 10) * 16;

    const int t = threadIdx.x;

    const short* xh_b = xT  + (size_t)b * HW * Cc;
    const short* xl_b = xLo + (size_t)b * HW * Cc;
#pragma unroll
    for (int j = 0; j < 14; ++j) {
        int ci = j * 256 + t;
        if (ci < 3456) {
            int slot = ci / 576;
            int rem2 = ci % 576;
            int isLo = rem2 >= 288;
            int cj   = isLo ? rem2 - 288 : rem2;
            int pxl  = cj >> 4;
            int ck   = cj & 15;
            int r   = h0 - 1 + slot;
            int col = w0 - 1 + pxl;
            int4 v = make_int4(0, 0, 0, 0);
            if ((unsigned)r < (unsigned)Hh && (unsigned)col < (unsigned)Ww) {
                const short* src = (isLo ? xl_b : xh_b) +
                                   ((size_t)(r * Ww + col)) * Cc + ck * 8;
                v = *(const int4*)src;
            }
            int byte = (pxl * 256 + ck * 16) ^ ((pxl & 7) << 4);
            *(int4*)((char*)(isLo ? a_lo[slot] : a_hi[slot]) + byte) = v;
        }
    }
    __syncthreads();

    const int lane = t & 63, wid = t >> 6;
    const int i  = lane & 15;
    const int kb = (lane >> 4) * 8;

    f32x4 acc[2];
    acc[0] = (f32x4){0.f, 0.f, 0.f, 0.f};
    acc[1] = (f32x4){0.f, 0.f, 0.f, 0.f};

    s16x8 bh[2][2][4], bl[2][2][4];

#pragma unroll
    for (int tile = 0; tile < 2; ++tile) {
        const short* bp = wh + ((size_t)(tile * 16 + i)) * Cc + kb;
        const short* lp = wl + ((size_t)(tile * 16 + i)) * Cc + kb;
#pragma unroll
        for (int kk = 0; kk < 4; ++kk) {
            bh[0][tile][kk] = *(const s16x8*)(bp + kk * 32);
            bl[0][tile][kk] = *(const s16x8*)(lp + kk * 32);
        }
    }

#pragma unroll
    for (int k = 0; k < Kk; ++k) {
        const int cur = k & 1, nxt = cur ^ 1;
        if (k < Kk - 1) {
            const int kn = k + 1;
#pragma unroll
            for (int tile = 0; tile < 2; ++tile) {
                const short* bp = wh + ((size_t)(kn * 32 + tile * 16 + i)) * Cc + kb;
                const short* lp = wl + ((size_t)(kn * 32 + tile * 16 + i)) * Cc + kb;
#pragma unroll
                for (int kk = 0; kk < 4; ++kk) {
                    bh[nxt][tile][kk] = *(const s16x8*)(bp + kk * 32);
                    bl[nxt][tile][kk] = *(const s16x8*)(lp + kk * 32);
                }
            }
        }
        const int ky = k / 3, kxi = k % 3;
        const int slot = wid + ky;
        const int pxl = i + kxi;
        s16x8 ah[4], al[4];
#pragma unroll
        for (int kk = 0; kk < 4; ++kk) {
            int byte = (pxl * 256 + (kk * 32 + kb) * 2) ^ ((pxl & 7) << 4);
            ah[kk] = *(const s16x8*)((char*)a_hi[slot] + byte);
            al[kk] = *(const s16x8*)((char*)a_lo[slot] + byte);
        }
#pragma unroll
        for (int tile = 0; tile < 2; ++tile) {
#pragma unroll
            for (int kk = 0; kk < 4; ++kk) {
                acc[tile] = __builtin_amdgcn_mfma_f32_16x16x32_bf16(ah[kk], bh[cur][tile][kk], acc[tile], 0, 0, 0);
                acc[tile] = __builtin_amdgcn_mfma_f32_16x16x32_bf16(al[kk], bh[cur][tile][kk], acc[tile], 0, 0, 0);
                acc[tile] = __builtin_amdgcn_mfma_f32_16x16x32_bf16(ah[kk], bl[cur][tile][kk], acc[tile], 0, 0, 0);
            }
        }
    }

    const int hr = h0 + wid;
#pragma unroll
    for (int tile = 0; tile < 2; ++tile) {
        int ch = tile * 16 + i;
#pragma unroll
        for (int reg = 0; reg < 4; ++reg) {
            int pxo = (lane >> 4) * 4 + reg;
            int p = hr * Ww + w0 + pxo;
            float v = acc[tile][reg];
            if (ch < 18) {
                int k = ch >> 1;
                v += b_off[ch];
                if (ch & 1) dx_o[(size_t)(b * 9 + k) * HW + p] = v;
                else        dy_o[(size_t)(b * 9 + k) * HW + p] = v;
            } else if (ch < 27) {
                int k = ch - 18;
                v += b_mask[k];
                mk_o[(size_t)(b * 9 + k) * HW + p] = 1.f / (1.f + expf(-v));
            }
        }
    }
}

// ---------------------------------------------------------------------------
// Kernel C: main deformable conv — r13 body with ONE occupancy edit:
// SINGLE-buffered w_lds (32 KB instead of 2x32), staged via registers
// (LOADW at top of iter k -> ds_write after a post-MFMA barrier). LDS was
// the sole occupancy limiter (VGPR=112): 64->32 KB lifts 2->4 blocks/CU
// (__launch_bounds__(256,4), 16 waves/CU). Cost: +1 barrier/k.
// Numerics identical to r13.
// ---------------------------------------------------------------------------
__global__ __launch_bounds__(256, 4) void dconv_main(
    const short* __restrict__ xT,    // [b][hw][c] bf16
    const short* __restrict__ wb,    // [k][o][c] bf16
    const float* __restrict__ bias,
    const float* __restrict__ dy_i, const float* __restrict__ dx_i,
    const float* __restrict__ mk_i,
    float* __restrict__ out)
{
    __shared__ short w_lds[128 * 128];   // 32 KB, byte ^= (o&15)<<4

    const int g = blockIdx.x;
    const int orig = (g & 7) * 200 + (g >> 3);
    const int b = orig / 400;
    const int rem = orig % 400;
    const int h0 = (rem / 10) * 4;
    const int w0 = (rem % 10) * 16;

    const int t = threadIdx.x;
    const int lane = t & 63;
    const int wid = t >> 6;

    const int i16 = lane & 15;
    const int h = h0 + wid;
    const int w = w0 + i16;
    const int p = h * Ww + w;
    const int kb8 = (lane >> 4) * 8;

    const short* xbase = xT + (size_t)b * HW * Cc + kb8;

    f32x4 acc[8];
#pragma unroll
    for (int i = 0; i < 8; ++i) acc[i] = (f32x4){0.f, 0.f, 0.f, 0.f};

    float wgbuf[2][4];
    int   idxc[4];
    s16x8 G[2][16];
    float omv[2][3];
    int4  Wr[8];

#define SETUP(kq, wbuf, dyv, dxv, mv)                                          \
    {                                                                          \
        float py  = (float)(h + ((kq) / 3) - 1) + (dyv);                       \
        float pxf = (float)(w + ((kq) % 3) - 1) + (dxv);                       \
        float y0f = floorf(py), x0f = floorf(pxf);                             \
        float ly = py - y0f, lx = pxf - x0f;                                   \
        int y0 = (int)y0f, x0 = (int)x0f;                                      \
        _Pragma("unroll")                                                      \
        for (int cr = 0; cr < 4; ++cr) {                                       \
            int iy = y0 + (cr >> 1), ix = x0 + (cr & 1);                       \
            bool ok = ((unsigned)iy < (unsigned)Hh) && ((unsigned)ix < (unsigned)Ww); \
            float wy = (cr >> 1) ? ly : (1.f - ly);                            \
            float wx = (cr & 1) ? lx : (1.f - lx);                             \
            int cy = min(max(iy, 0), Hh - 1);                                  \
            int cx = min(max(ix, 0), Ww - 1);                                  \
            idxc[cr] = cy * Ww + cx;                                           \
            wgbuf[wbuf][cr] = ok ? (wy * wx * (mv)) : 0.f;                     \
        }                                                                      \
    }

#define ISSUEG(gbuf)                                                           \
    {                                                                          \
        _Pragma("unroll")                                                      \
        for (int cr = 0; cr < 4; ++cr) {                                       \
            const short* src = xbase + (size_t)idxc[cr] * Cc;                  \
            _Pragma("unroll")                                                  \
            for (int kk = 0; kk < 4; ++kk)                                     \
                G[gbuf][cr * 4 + kk] = *(const s16x8*)(src + kk * 32);         \
        }                                                                      \
    }

#define LOADOM(kq, obuf)                                                       \
    {                                                                          \
        size_t ob = (size_t)(b * 9 + (kq)) * HW + p;                           \
        omv[obuf][0] = dy_i[ob]; omv[obuf][1] = dx_i[ob]; omv[obuf][2] = mk_i[ob]; \
    }

#define LOADW(kq)                                                              \
    {                                                                          \
        const int4* src = (const int4*)(wb + (size_t)(kq) * 128 * 128);        \
        _Pragma("unroll")                                                      \
        for (int i2 = 0; i2 < 8; ++i2) Wr[i2] = src[i2 * 256 + t];             \
    }

#define WRITEW                                                                 \
    {                                                                          \
        _Pragma("unroll")                                                      \
        for (int i2 = 0; i2 < 8; ++i2) {                                       \
            int ci = i2 * 256 + t;                                             \
            int o = ci >> 4;                                                   \
            int byte = (ci << 4) ^ ((o & 15) << 4);                            \
            *(int4*)((char*)w_lds + byte) = Wr[i2];                            \
        }                                                                      \
    }

    // ---- prologue: tap 0 fully prepared ----
    LOADW(0);
    LOADOM(0, 0);
    LOADOM(1, 1);
    SETUP(0, 0, omv[0][0], omv[0][1], omv[0][2]);
    ISSUEG(0);
    WRITEW;
    __syncthreads();

#pragma unroll
    for (int k = 0; k < Kk; ++k) {
        // ---- top-of-iter issues: land during blend+MFMA ----
        if (k < Kk - 1) LOADW(k + 1);
        if (k < Kk - 2) LOADOM(k + 2, k & 1);
        if (k < Kk - 1) {
            SETUP(k + 1, (k + 1) & 1,
                  omv[(k + 1) & 1][0], omv[(k + 1) & 1][1], omv[(k + 1) & 1][2]);
            ISSUEG((k + 1) & 1);
        }

        // ---- blend(k): consumes G[k&1], wgbuf[k&1] (landed last iter) ----
        s16x8 afr[4];
#pragma unroll
        for (int kk = 0; kk < 4; ++kk) {
#pragma unroll
            for (int j = 0; j < 8; ++j) {
                float sv = wgbuf[k & 1][0] * bf2f(G[k & 1][0 * 4 + kk][j])
                         + wgbuf[k & 1][1] * bf2f(G[k & 1][1 * 4 + kk][j])
                         + wgbuf[k & 1][2] * bf2f(G[k & 1][2 * 4 + kk][j])
                         + wgbuf[k & 1][3] * bf2f(G[k & 1][3 * 4 + kk][j]);
                afr[kk][j] = f2bf(sv);
            }
        }

        // ---- MFMA(k): A in regs, B from the single w_lds ----
        {
            const int orow = lane & 15;
#pragma unroll
            for (int ot = 0; ot < 8; ++ot) {
                int o = ot * 16 + orow;
#pragma unroll
                for (int kk = 0; kk < 4; ++kk) {
                    int byte = (o * 256 + (kk * 32 + kb8) * 2) ^ ((o & 15) << 4);
                    s16x8 bfr = *(const s16x8*)((char*)w_lds + byte);
                    acc[ot] = __builtin_amdgcn_mfma_f32_16x16x32_bf16(afr[kk], bfr, acc[ot], 0, 0, 0);
                }
            }
        }

        // ---- single-buffer rotation: reads done -> overwrite -> visible ----
        if (k < Kk - 1) {
            __syncthreads();   // all waves' w_lds reads of tap k complete
            WRITEW;            // Wr (issued at top) long since landed
            __syncthreads();   // tap k+1 weights visible
        }
    }

#undef SETUP
#undef ISSUEG
#undef LOADOM
#undef LOADW
#undef WRITEW

    // ---- epilogue ----
#pragma unroll
    for (int ot = 0; ot < 8; ++ot) {
        int o = ot * 16 + (lane & 15);
        float bo = bias[o];
        float4 r;
        r.x = acc[ot][0] + bo;
        r.y = acc[ot][1] + bo;
        r.z = acc[ot][2] + bo;
        r.w = acc[ot][3] + bo;
        *(float4*)(out + ((size_t)(b * On + o)) * HW + h * Ww + w0 + (lane >> 4) * 4) = r;
    }
}

// ---------------------------------------------------------------------------
extern "C" void kernel_launch(void* const* d_in, const int* in_sizes, int n_in,
                              void* d_out, int out_size, void* d_ws, size_t ws_size,
                              hipStream_t stream) {
    const float* x      = (const float*)d_in[0];
    const float* w_off  = (const float*)d_in[1];
    const float* b_off  = (const float*)d_in[2];
    const float* w_mask = (const float*)d_in[3];
    const float* b_mask = (const float*)d_in[4];
    const float* wt     = (const float*)d_in[5];
    const float* bias   = (const float*)d_in[6];
    float* out = (float*)d_out;

    short* xT  = (short*)d_ws;                      // B*HW*C bf16 hi
    short* xLo = xT + (size_t)Bn * HW * Cc;         // B*HW*C bf16 lo
    short* wb  = xLo + (size_t)Bn * HW * Cc;        // K*O*C bf16
    short* wofm_h = wb + Kk * On * Cc;
    short* wofm_l = wofm_h + Kk * 32 * Cc;
    float* dy = (float*)(wofm_l + Kk * 32 * Cc);
    float* dx = dy + (size_t)Bn * 9 * HW;
    float* mk = dx + (size_t)Bn * 9 * HW;

    to_nhwc<<<dim3(HW / 64, Bn), 256, 0, stream>>>(x, xT, xLo);
    prep_w<<<(Kk * On * Cc + 255) / 256, 256, 0, stream>>>(wt, wb);
    prep_wofm<<<(Kk * 32 * Cc + 255) / 256, 256, 0, stream>>>(w_off, w_mask, wofm_h, wofm_l);
    offmask_mfma<<<1600, 256, 0, stream>>>(
        xT, xLo, wofm_h, wofm_l, b_off, b_mask, dy, dx, mk);
    dconv_main<<<1600, 256, 0, stream>>>(
        xT, wb, bias, dy, dx, mk, out);
}

// Round 17
// 453.814 us; speedup vs baseline: 1.2489x; 1.2489x over previous
//
#include <hip/hip_runtime.h>
#include <math.h>

constexpr int Bn = 4, Cc = 128, On = 128, Hh = 160, Ww = 160, Kk = 9;
constexpr int HW = Hh * Ww;          // 25600

typedef __attribute__((ext_vector_type(8))) short s16x8;
typedef __attribute__((ext_vector_type(4))) float f32x4;

__device__ inline float bf2f(short s) {
    union { float f; unsigned u; } v;
    v.u = ((unsigned)(unsigned short)s) << 16;
    return v.f;
}
__device__ inline short f2bf(float f) {
    union { float f; unsigned u; } v;
    v.f = f;
    unsigned r = v.u + 0x7fffu + ((v.u >> 16) & 1u);   // RNE
    return (short)(r >> 16);
}

// ---------------------------------------------------------------------------
// Kernel A1: x (NCHW f32) -> xT (NHWC bf16 hi) + xLo (NHWC bf16 lo).
// ---------------------------------------------------------------------------
__global__ __launch_bounds__(256) void to_nhwc(const float* __restrict__ x,
                                               short* __restrict__ xT,
                                               short* __restrict__ xLo) {
    __shared__ float tile[128][65];
    const int t = threadIdx.x;
    const int p0 = blockIdx.x * 64;
    const int b = blockIdx.y;
#pragma unroll
    for (int i = 0; i < 32; ++i) {
        int c = i * 4 + (t >> 6);
        tile[c][t & 63] = x[((size_t)b * Cc + c) * HW + p0 + (t & 63)];
    }
    __syncthreads();
    const int px = t >> 2, cq = t & 3;
    short* dsth = xT  + ((size_t)(b * HW) + p0 + px) * Cc;
    short* dstl = xLo + ((size_t)(b * HW) + p0 + px) * Cc;
#pragma unroll
    for (int j = 0; j < 8; ++j) {
        int c0 = cq * 4 + j * 16;
        short4 vh, vl;
        float f0 = tile[c0 + 0][px], f1 = tile[c0 + 1][px];
        float f2 = tile[c0 + 2][px], f3 = tile[c0 + 3][px];
        vh.x = f2bf(f0); vh.y = f2bf(f1); vh.z = f2bf(f2); vh.w = f2bf(f3);
        vl.x = f2bf(f0 - bf2f(vh.x));
        vl.y = f2bf(f1 - bf2f(vh.y));
        vl.z = f2bf(f2 - bf2f(vh.z));
        vl.w = f2bf(f3 - bf2f(vh.w));
        *(short4*)(dsth + c0) = vh;
        *(short4*)(dstl + c0) = vl;
    }
}

// ---------------------------------------------------------------------------
// Kernel A2: wt (O,C,3,3) f32 -> wb[k][o][c] bf16
// ---------------------------------------------------------------------------
__global__ void prep_w(const float* __restrict__ wt, short* __restrict__ wb) {
    int idx = blockIdx.x * 256 + threadIdx.x;     // K*O*C = 147456
    if (idx >= Kk * On * Cc) return;
    int c = idx & 127;
    int o = (idx >> 7) & 127;
    int k = idx >> 14;
    wb[idx] = f2bf(wt[(o * Cc + c) * 9 + k]);
}

// ---------------------------------------------------------------------------
// Kernel A3: offset/mask weights -> wofm_{hi,lo}[k][ch32][c].
// ---------------------------------------------------------------------------
__global__ void prep_wofm(const float* __restrict__ w_off,
                          const float* __restrict__ w_mask,
                          short* __restrict__ wh, short* __restrict__ wl) {
    int idx = blockIdx.x * 256 + threadIdx.x;     // 9*32*128 = 36864
    if (idx >= Kk * 32 * Cc) return;
    int c = idx & 127;
    int ch = (idx >> 7) & 31;
    int k = idx >> 12;
    float v = 0.f;
    if (ch < 18)      v = w_off[(ch * Cc + c) * 9 + k];
    else if (ch < 27) v = w_mask[((ch - 18) * Cc + c) * 9 + k];
    short hi = f2bf(v);
    wh[idx] = hi;
    wl[idx] = f2bf(v - bf2f(hi));
}

// ---------------------------------------------------------------------------
// Kernel B: offset/mask conv via MFMA, hi/lo split (r13 version, unchanged).
// ---------------------------------------------------------------------------
__global__ __launch_bounds__(256) void offmask_mfma(
    const short* __restrict__ xT, const short* __restrict__ xLo,
    const short* __restrict__ wh, const short* __restrict__ wl,
    const float* __restrict__ b_off, const float* __restrict__ b_mask,
    float* __restrict__ dy_o, float* __restrict__ dx_o, float* __restrict__ mk_o)
{
    __shared__ short a_hi[6][2304];
    __shared__ short a_lo[6][2304];

    const int g = blockIdx.x;
    const int orig = (g & 7) * 200 + (g >> 3);
    const int b  = orig / 400;
    const int rem = orig % 400;
    const int h0 = (rem / 10) * 4;
    const int w0 = (rem % 10) * 16;

    const int t = threadIdx.x;

    const short* xh_b = xT  + (size_t)b * HW * Cc;
    const short* xl_b = xLo + (size_t)b * HW * Cc;
#pragma unroll
    for (int j = 0; j < 14; ++j) {
        int ci = j * 256 + t;
        if (ci < 3456) {
            int slot = ci / 576;
            int rem2 = ci % 576;
            int isLo = rem2 >= 288;
            int cj   = isLo ? rem2 - 288 : rem2;
            int pxl  = cj >> 4;
            int ck   = cj & 15;
            int r   = h0 - 1 + slot;
            int col = w0 - 1 + pxl;
            int4 v = make_int4(0, 0, 0, 0);
            if ((unsigned)r < (unsigned)Hh && (unsigned)col < (unsigned)Ww) {
                const short* src = (isLo ? xl_b : xh_b) +
                                   ((size_t)(r * Ww + col)) * Cc + ck * 8;
                v = *(const int4*)src;
            }
            int byte = (pxl * 256 + ck * 16) ^ ((pxl & 7) << 4);
            *(int4*)((char*)(isLo ? a_lo[slot] : a_hi[slot]) + byte) = v;
        }
    }
    __syncthreads();

    const int lane = t & 63, wid = t >> 6;
    const int i  = lane & 15;
    const int kb = (lane >> 4) * 8;

    f32x4 acc[2];
    acc[0] = (f32x4){0.f, 0.f, 0.f, 0.f};
    acc[1] = (f32x4){0.f, 0.f, 0.f, 0.f};

    s16x8 bh[2][2][4], bl[2][2][4];

#pragma unroll
    for (int tile = 0; tile < 2; ++tile) {
        const short* bp = wh + ((size_t)(tile * 16 + i)) * Cc + kb;
        const short* lp = wl + ((size_t)(tile * 16 + i)) * Cc + kb;
#pragma unroll
        for (int kk = 0; kk < 4; ++kk) {
            bh[0][tile][kk] = *(const s16x8*)(bp + kk * 32);
            bl[0][tile][kk] = *(const s16x8*)(lp + kk * 32);
        }
    }

#pragma unroll
    for (int k = 0; k < Kk; ++k) {
        const int cur = k & 1, nxt = cur ^ 1;
        if (k < Kk - 1) {
            const int kn = k + 1;
#pragma unroll
            for (int tile = 0; tile < 2; ++tile) {
                const short* bp = wh + ((size_t)(kn * 32 + tile * 16 + i)) * Cc + kb;
                const short* lp = wl + ((size_t)(kn * 32 + tile * 16 + i)) * Cc + kb;
#pragma unroll
                for (int kk = 0; kk < 4; ++kk) {
                    bh[nxt][tile][kk] = *(const s16x8*)(bp + kk * 32);
                    bl[nxt][tile][kk] = *(const s16x8*)(lp + kk * 32);
                }
            }
        }
        const int ky = k / 3, kxi = k % 3;
        const int slot = wid + ky;
        const int pxl = i + kxi;
        s16x8 ah[4], al[4];
#pragma unroll
        for (int kk = 0; kk < 4; ++kk) {
            int byte = (pxl * 256 + (kk * 32 + kb) * 2) ^ ((pxl & 7) << 4);
            ah[kk] = *(const s16x8*)((char*)a_hi[slot] + byte);
            al[kk] = *(const s16x8*)((char*)a_lo[slot] + byte);
        }
#pragma unroll
        for (int tile = 0; tile < 2; ++tile) {
#pragma unroll
            for (int kk = 0; kk < 4; ++kk) {
                acc[tile] = __builtin_amdgcn_mfma_f32_16x16x32_bf16(ah[kk], bh[cur][tile][kk], acc[tile], 0, 0, 0);
                acc[tile] = __builtin_amdgcn_mfma_f32_16x16x32_bf16(al[kk], bh[cur][tile][kk], acc[tile], 0, 0, 0);
                acc[tile] = __builtin_amdgcn_mfma_f32_16x16x32_bf16(ah[kk], bl[cur][tile][kk], acc[tile], 0, 0, 0);
            }
        }
    }

    const int hr = h0 + wid;
#pragma unroll
    for (int tile = 0; tile < 2; ++tile) {
        int ch = tile * 16 + i;
#pragma unroll
        for (int reg = 0; reg < 4; ++reg) {
            int pxo = (lane >> 4) * 4 + reg;
            int p = hr * Ww + w0 + pxo;
            float v = acc[tile][reg];
            if (ch < 18) {
                int k = ch >> 1;
                v += b_off[ch];
                if (ch & 1) dx_o[(size_t)(b * 9 + k) * HW + p] = v;
                else        dy_o[(size_t)(b * 9 + k) * HW + p] = v;
            } else if (ch < 27) {
                int k = ch - 18;
                v += b_mask[k];
                mk_o[(size_t)(b * 9 + k) * HW + p] = 1.f / (1.f + expf(-v));
            }
        }
    }
}

// ---------------------------------------------------------------------------
// Kernel C: main deformable conv — occupancy experiment, spill-safe:
//  - single 32 KB w_lds, rotation: barrier -> WRITEW -> barrier
//  - SINGLE G[16] (64 VGPR): ISSUEG(k+1) after blend(k) (single wg too)
//  - __launch_bounds__(256,3): 3 blocks/CU (12 waves), budget ~170 VGPR,
//    static demand ~160 -> no spills (check: FETCH_SIZE must stay ~21 MB).
// Numerics identical to r13.
// ---------------------------------------------------------------------------
__global__ __launch_bounds__(256, 3) void dconv_main(
    const short* __restrict__ xT,    // [b][hw][c] bf16
    const short* __restrict__ wb,    // [k][o][c] bf16
    const float* __restrict__ bias,
    const float* __restrict__ dy_i, const float* __restrict__ dx_i,
    const float* __restrict__ mk_i,
    float* __restrict__ out)
{
    __shared__ short w_lds[128 * 128];   // 32 KB, byte ^= (o&15)<<4

    const int g = blockIdx.x;
    const int orig = (g & 7) * 200 + (g >> 3);
    const int b = orig / 400;
    const int rem = orig % 400;
    const int h0 = (rem / 10) * 4;
    const int w0 = (rem % 10) * 16;

    const int t = threadIdx.x;
    const int lane = t & 63;
    const int wid = t >> 6;

    const int i16 = lane & 15;
    const int h = h0 + wid;
    const int w = w0 + i16;
    const int p = h * Ww + w;
    const int kb8 = (lane >> 4) * 8;

    const short* xbase = xT + (size_t)b * HW * Cc + kb8;

    f32x4 acc[8];
#pragma unroll
    for (int i = 0; i < 8; ++i) acc[i] = (f32x4){0.f, 0.f, 0.f, 0.f};

    float wg[4];
    int   idxc[4];
    s16x8 G[16];
    float omv[2][3];
    int4  Wr[8];

#define SETUP(kq, dyv, dxv, mv)                                                \
    {                                                                          \
        float py  = (float)(h + ((kq) / 3) - 1) + (dyv);                       \
        float pxf = (float)(w + ((kq) % 3) - 1) + (dxv);                       \
        float y0f = floorf(py), x0f = floorf(pxf);                             \
        float ly = py - y0f, lx = pxf - x0f;                                   \
        int y0 = (int)y0f, x0 = (int)x0f;                                      \
        _Pragma("unroll")                                                      \
        for (int cr = 0; cr < 4; ++cr) {                                       \
            int iy = y0 + (cr >> 1), ix = x0 + (cr & 1);                       \
            bool ok = ((unsigned)iy < (unsigned)Hh) && ((unsigned)ix < (unsigned)Ww); \
            float wy = (cr >> 1) ? ly : (1.f - ly);                            \
            float wx = (cr & 1) ? lx : (1.f - lx);                             \
            int cy = min(max(iy, 0), Hh - 1);                                  \
            int cx = min(max(ix, 0), Ww - 1);                                  \
            idxc[cr] = cy * Ww + cx;                                           \
            wg[cr] = ok ? (wy * wx * (mv)) : 0.f;                              \
        }                                                                      \
    }

#define ISSUEG                                                                 \
    {                                                                          \
        _Pragma("unroll")                                                      \
        for (int cr = 0; cr < 4; ++cr) {                                       \
            const short* src = xbase + (size_t)idxc[cr] * Cc;                  \
            _Pragma("unroll")                                                  \
            for (int kk = 0; kk < 4; ++kk)                                     \
                G[cr * 4 + kk] = *(const s16x8*)(src + kk * 32);               \
        }                                                                      \
    }

#define LOADOM(kq, obuf)                                                       \
    {                                                                          \
        size_t ob = (size_t)(b * 9 + (kq)) * HW + p;                           \
        omv[obuf][0] = dy_i[ob]; omv[obuf][1] = dx_i[ob]; omv[obuf][2] = mk_i[ob]; \
    }

#define LOADW(kq)                                                              \
    {                                                                          \
        const int4* src = (const int4*)(wb + (size_t)(kq) * 128 * 128);        \
        _Pragma("unroll")                                                      \
        for (int i2 = 0; i2 < 8; ++i2) Wr[i2] = src[i2 * 256 + t];             \
    }

#define WRITEW                                                                 \
    {                                                                          \
        _Pragma("unroll")                                                      \
        for (int i2 = 0; i2 < 8; ++i2) {                                       \
            int ci = i2 * 256 + t;                                             \
            int o = ci >> 4;                                                   \
            int byte = (ci << 4) ^ ((o & 15) << 4);                            \
            *(int4*)((char*)w_lds + byte) = Wr[i2];                            \
        }                                                                      \
    }

    // ---- prologue: tap 0 fully prepared ----
    LOADW(0);
    LOADOM(0, 0);
    LOADOM(1, 1);
    SETUP(0, omv[0][0], omv[0][1], omv[0][2]);
    ISSUEG;
    WRITEW;
    __syncthreads();

#pragma unroll
    for (int k = 0; k < Kk; ++k) {
        // ---- long-lead issues for k+1 / k+2 ----
        if (k < Kk - 1) LOADW(k + 1);
        if (k < Kk - 2) LOADOM(k + 2, k & 1);

        // ---- blend(k): consumes G, wg (tap k) ----
        s16x8 afr[4];
#pragma unroll
        for (int kk = 0; kk < 4; ++kk) {
#pragma unroll
            for (int j = 0; j < 8; ++j) {
                float sv = wg[0] * bf2f(G[0 * 4 + kk][j])
                         + wg[1] * bf2f(G[1 * 4 + kk][j])
                         + wg[2] * bf2f(G[2 * 4 + kk][j])
                         + wg[3] * bf2f(G[3 * 4 + kk][j]);
                afr[kk][j] = f2bf(sv);
            }
        }

        // ---- setup + gathers for k+1 (G/wg free now) ----
        if (k < Kk - 1) {
            SETUP(k + 1, omv[(k + 1) & 1][0], omv[(k + 1) & 1][1], omv[(k + 1) & 1][2]);
            ISSUEG;
        }

        // ---- MFMA(k): A in regs, B from the single w_lds ----
        {
            const int orow = lane & 15;
#pragma unroll
            for (int ot = 0; ot < 8; ++ot) {
                int o = ot * 16 + orow;
#pragma unroll
                for (int kk = 0; kk < 4; ++kk) {
                    int byte = (o * 256 + (kk * 32 + kb8) * 2) ^ ((o & 15) << 4);
                    s16x8 bfr = *(const s16x8*)((char*)w_lds + byte);
                    acc[ot] = __builtin_amdgcn_mfma_f32_16x16x32_bf16(afr[kk], bfr, acc[ot], 0, 0, 0);
                }
            }
        }

        // ---- single-buffer rotation ----
        if (k < Kk - 1) {
            __syncthreads();   // all waves' w_lds reads of tap k complete
            WRITEW;            // Wr (issued at top) long since landed
            __syncthreads();   // tap k+1 weights visible
        }
    }

#undef SETUP
#undef ISSUEG
#undef LOADOM
#undef LOADW
#undef WRITEW

    // ---- epilogue ----
#pragma unroll
    for (int ot = 0; ot < 8; ++ot) {
        int o = ot * 16 + (lane & 15);
        float bo = bias[o];
        float4 r;
        r.x = acc[ot][0] + bo;
        r.y = acc[ot][1] + bo;
        r.z = acc[ot][2] + bo;
        r.w = acc[ot][3] + bo;
        *(float4*)(out + ((size_t)(b * On + o)) * HW + h * Ww + w0 + (lane >> 4) * 4) = r;
    }
}

// ---------------------------------------------------------------------------
extern "C" void kernel_launch(void* const* d_in, const int* in_sizes, int n_in,
                              void* d_out, int out_size, void* d_ws, size_t ws_size,
                              hipStream_t stream) {
    const float* x      = (const float*)d_in[0];
    const float* w_off  = (const float*)d_in[1];
    const float* b_off  = (const float*)d_in[2];
    const float* w_mask = (const float*)d_in[3];
    const float* b_mask = (const float*)d_in[4];
    const float* wt     = (const float*)d_in[5];
    const float* bias   = (const float*)d_in[6];
    float* out = (float*)d_out;

    short* xT  = (short*)d_ws;                      // B*HW*C bf16 hi
    short* xLo = xT + (size_t)Bn * HW * Cc;         // B*HW*C bf16 lo
    short* wb  = xLo + (size_t)Bn * HW * Cc;        // K*O*C bf16
    short* wofm_h = wb + Kk * On * Cc;
    short* wofm_l = wofm_h + Kk * 32 * Cc;
    float* dy = (float*)(wofm_l + Kk * 32 * Cc);
    float* dx = dy + (size_t)Bn * 9 * HW;
    float* mk = dx + (size_t)Bn * 9 * HW;

    to_nhwc<<<dim3(HW / 64, Bn), 256, 0, stream>>>(x, xT, xLo);
    prep_w<<<(Kk * On * Cc + 255) / 256, 256, 0, stream>>>(wt, wb);
    prep_wofm<<<(Kk * 32 * Cc + 255) / 256, 256, 0, stream>>>(w_off, w_mask, wofm_h, wofm_l);
    offmask_mfma<<<1600, 256, 0, stream>>>(
        xT, xLo, wofm_h, wofm_l, b_off, b_mask, dy, dx, mk);
    dconv_main<<<1600, 256, 0, stream>>>(
        xT, wb, bias, dy, dx, mk, out);
}

// Round 18
// 336.327 us; speedup vs baseline: 1.6851x; 1.3493x over previous
//
#include <hip/hip_runtime.h>
#include <math.h>

constexpr int Bn = 4, Cc = 128, On = 128, Hh = 160, Ww = 160, Kk = 9;
constexpr int HW = Hh * Ww;          // 25600

typedef __attribute__((ext_vector_type(8))) short s16x8;
typedef __attribute__((ext_vector_type(4))) float f32x4;

__device__ inline float bf2f(short s) {
    union { float f; unsigned u; } v;
    v.u = ((unsigned)(unsigned short)s) << 16;
    return v.f;
}
__device__ inline short f2bf(float f) {
    union { float f; unsigned u; } v;
    v.f = f;
    unsigned r = v.u + 0x7fffu + ((v.u >> 16) & 1u);   // RNE
    return (short)(r >> 16);
}

// ---------------------------------------------------------------------------
// Kernel A1: x (NCHW f32) -> xT (NHWC bf16 hi) + xLo (NHWC bf16 lo).
// ---------------------------------------------------------------------------
__global__ __launch_bounds__(256) void to_nhwc(const float* __restrict__ x,
                                               short* __restrict__ xT,
                                               short* __restrict__ xLo) {
    __shared__ float tile[128][65];
    const int t = threadIdx.x;
    const int p0 = blockIdx.x * 64;
    const int b = blockIdx.y;
#pragma unroll
    for (int i = 0; i < 32; ++i) {
        int c = i * 4 + (t >> 6);
        tile[c][t & 63] = x[((size_t)b * Cc + c) * HW + p0 + (t & 63)];
    }
    __syncthreads();
    const int px = t >> 2, cq = t & 3;
    short* dsth = xT  + ((size_t)(b * HW) + p0 + px) * Cc;
    short* dstl = xLo + ((size_t)(b * HW) + p0 + px) * Cc;
#pragma unroll
    for (int j = 0; j < 8; ++j) {
        int c0 = cq * 4 + j * 16;
        short4 vh, vl;
        float f0 = tile[c0 + 0][px], f1 = tile[c0 + 1][px];
        float f2 = tile[c0 + 2][px], f3 = tile[c0 + 3][px];
        vh.x = f2bf(f0); vh.y = f2bf(f1); vh.z = f2bf(f2); vh.w = f2bf(f3);
        vl.x = f2bf(f0 - bf2f(vh.x));
        vl.y = f2bf(f1 - bf2f(vh.y));
        vl.z = f2bf(f2 - bf2f(vh.z));
        vl.w = f2bf(f3 - bf2f(vh.w));
        *(short4*)(dsth + c0) = vh;
        *(short4*)(dstl + c0) = vl;
    }
}

// ---------------------------------------------------------------------------
// Kernel A2: wt (O,C,3,3) f32 -> wb[k][o][c] bf16
// ---------------------------------------------------------------------------
__global__ void prep_w(const float* __restrict__ wt, short* __restrict__ wb) {
    int idx = blockIdx.x * 256 + threadIdx.x;     // K*O*C = 147456
    if (idx >= Kk * On * Cc) return;
    int c = idx & 127;
    int o = (idx >> 7) & 127;
    int k = idx >> 14;
    wb[idx] = f2bf(wt[(o * Cc + c) * 9 + k]);
}

// ---------------------------------------------------------------------------
// Kernel A3: offset/mask weights -> wofm_{hi,lo}[k][ch32][c].
// ---------------------------------------------------------------------------
__global__ void prep_wofm(const float* __restrict__ w_off,
                          const float* __restrict__ w_mask,
                          short* __restrict__ wh, short* __restrict__ wl) {
    int idx = blockIdx.x * 256 + threadIdx.x;     // 9*32*128 = 36864
    if (idx >= Kk * 32 * Cc) return;
    int c = idx & 127;
    int ch = (idx >> 7) & 31;
    int k = idx >> 12;
    float v = 0.f;
    if (ch < 18)      v = w_off[(ch * Cc + c) * 9 + k];
    else if (ch < 27) v = w_mask[((ch - 18) * Cc + c) * 9 + k];
    short hi = f2bf(v);
    wh[idx] = hi;
    wl[idx] = f2bf(v - bf2f(hi));
}

// ---------------------------------------------------------------------------
// Kernel B: offset/mask conv via MFMA, hi/lo split (r13 version, unchanged).
// ---------------------------------------------------------------------------
__global__ __launch_bounds__(256) void offmask_mfma(
    const short* __restrict__ xT, const short* __restrict__ xLo,
    const short* __restrict__ wh, const short* __restrict__ wl,
    const float* __restrict__ b_off, const float* __restrict__ b_mask,
    float* __restrict__ dy_o, float* __restrict__ dx_o, float* __restrict__ mk_o)
{
    __shared__ short a_hi[6][2304];
    __shared__ short a_lo[6][2304];

    const int g = blockIdx.x;
    const int orig = (g & 7) * 200 + (g >> 3);
    const int b  = orig / 400;
    const int rem = orig % 400;
    const int h0 = (rem / 10) * 4;
    const int w0 = (rem % 10) * 16;

    const int t = threadIdx.x;

    const short* xh_b = xT  + (size_t)b * HW * Cc;
    const short* xl_b = xLo + (size_t)b * HW * Cc;
#pragma unroll
    for (int j = 0; j < 14; ++j) {
        int ci = j * 256 + t;
        if (ci < 3456) {
            int slot = ci / 576;
            int rem2 = ci % 576;
            int isLo = rem2 >= 288;
            int cj   = isLo ? rem2 - 288 : rem2;
            int pxl  = cj >> 4;
            int ck   = cj & 15;
            int r   = h0 - 1 + slot;
            int col = w0 - 1 + pxl;
            int4 v = make_int4(0, 0, 0, 0);
            if ((unsigned)r < (unsigned)Hh && (unsigned)col < (unsigned)Ww) {
                const short* src = (isLo ? xl_b : xh_b) +
                                   ((size_t)(r * Ww + col)) * Cc + ck * 8;
                v = *(const int4*)src;
            }
            int byte = (pxl * 256 + ck * 16) ^ ((pxl & 7) << 4);
            *(int4*)((char*)(isLo ? a_lo[slot] : a_hi[slot]) + byte) = v;
        }
    }
    __syncthreads();

    const int lane = t & 63, wid = t >> 6;
    const int i  = lane & 15;
    const int kb = (lane >> 4) * 8;

    f32x4 acc[2];
    acc[0] = (f32x4){0.f, 0.f, 0.f, 0.f};
    acc[1] = (f32x4){0.f, 0.f, 0.f, 0.f};

    s16x8 bh[2][2][4], bl[2][2][4];

#pragma unroll
    for (int tile = 0; tile < 2; ++tile) {
        const short* bp = wh + ((size_t)(tile * 16 + i)) * Cc + kb;
        const short* lp = wl + ((size_t)(tile * 16 + i)) * Cc + kb;
#pragma unroll
        for (int kk = 0; kk < 4; ++kk) {
            bh[0][tile][kk] = *(const s16x8*)(bp + kk * 32);
            bl[0][tile][kk] = *(const s16x8*)(lp + kk * 32);
        }
    }

#pragma unroll
    for (int k = 0; k < Kk; ++k) {
        const int cur = k & 1, nxt = cur ^ 1;
        if (k < Kk - 1) {
            const int kn = k + 1;
#pragma unroll
            for (int tile = 0; tile < 2; ++tile) {
                const short* bp = wh + ((size_t)(kn * 32 + tile * 16 + i)) * Cc + kb;
                const short* lp = wl + ((size_t)(kn * 32 + tile * 16 + i)) * Cc + kb;
#pragma unroll
                for (int kk = 0; kk < 4; ++kk) {
                    bh[nxt][tile][kk] = *(const s16x8*)(bp + kk * 32);
                    bl[nxt][tile][kk] = *(const s16x8*)(lp + kk * 32);
                }
            }
        }
        const int ky = k / 3, kxi = k % 3;
        const int slot = wid + ky;
        const int pxl = i + kxi;
        s16x8 ah[4], al[4];
#pragma unroll
        for (int kk = 0; kk < 4; ++kk) {
            int byte = (pxl * 256 + (kk * 32 + kb) * 2) ^ ((pxl & 7) << 4);
            ah[kk] = *(const s16x8*)((char*)a_hi[slot] + byte);
            al[kk] = *(const s16x8*)((char*)a_lo[slot] + byte);
        }
#pragma unroll
        for (int tile = 0; tile < 2; ++tile) {
#pragma unroll
            for (int kk = 0; kk < 4; ++kk) {
                acc[tile] = __builtin_amdgcn_mfma_f32_16x16x32_bf16(ah[kk], bh[cur][tile][kk], acc[tile], 0, 0, 0);
                acc[tile] = __builtin_amdgcn_mfma_f32_16x16x32_bf16(al[kk], bh[cur][tile][kk], acc[tile], 0, 0, 0);
                acc[tile] = __builtin_amdgcn_mfma_f32_16x16x32_bf16(ah[kk], bl[cur][tile][kk], acc[tile], 0, 0, 0);
            }
        }
    }

    const int hr = h0 + wid;
#pragma unroll
    for (int tile = 0; tile < 2; ++tile) {
        int ch = tile * 16 + i;
#pragma unroll
        for (int reg = 0; reg < 4; ++reg) {
            int pxo = (lane >> 4) * 4 + reg;
            int p = hr * Ww + w0 + pxo;
            float v = acc[tile][reg];
            if (ch < 18) {
                int k = ch >> 1;
                v += b_off[ch];
                if (ch & 1) dx_o[(size_t)(b * 9 + k) * HW + p] = v;
                else        dy_o[(size_t)(b * 9 + k) * HW + p] = v;
            } else if (ch < 27) {
                int k = ch - 18;
                v += b_mask[k];
                mk_o[(size_t)(b * 9 + k) * HW + p] = 1.f / (1.f + expf(-v));
            }
        }
    }
}

// ---------------------------------------------------------------------------
// Kernel C: main deformable conv — r13 per-wave body UNCHANGED; block
// geometry change only: 512 threads = 8 waves, tile 8 rows x 16 cols.
// LDS (2x32 KB) is shared by 2x the pixels -> 2 blocks/CU now hold
// 16 waves/CU (occupancy x2) with IDENTICAL per-lane register demand
// (no launch-bounds squeeze -> no spills). Weight LOADW/WRITEW per pixel
// halves. Grid 800 (%8==0, swizzle bijective, 100 blocks/XCD).
// ---------------------------------------------------------------------------
__global__ __launch_bounds__(512) void dconv_main(
    const short* __restrict__ xT,    // [b][hw][c] bf16
    const short* __restrict__ wb,    // [k][o][c] bf16
    const float* __restrict__ bias,
    const float* __restrict__ dy_i, const float* __restrict__ dx_i,
    const float* __restrict__ mk_i,
    float* __restrict__ out)
{
    __shared__ short w_lds[2][128 * 128];   // 2 x 32 KB, byte ^= (o&15)<<4

    // XCD-chunked swizzle: 800 blocks = 8 XCDs x 100 contiguous (b,h0,w0).
    const int g = blockIdx.x;
    const int orig = (g & 7) * 100 + (g >> 3);
    const int b = orig / 200;
    const int rem = orig % 200;
    const int h0 = (rem / 10) * 8;       // 20 bands of 8 rows
    const int w0 = (rem % 10) * 16;      // 10 bands of 16 cols

    const int t = threadIdx.x;
    const int lane = t & 63;
    const int wid = t >> 6;              // 0..7

    const int i16 = lane & 15;
    const int h = h0 + wid;              // wave-uniform row
    const int w = w0 + i16;              // lane's column
    const int p = h * Ww + w;            // lane's global pixel
    const int kb8 = (lane >> 4) * 8;     // channel slice base

    const short* xbase = xT + (size_t)b * HW * Cc + kb8;

    f32x4 acc[8];
#pragma unroll
    for (int i = 0; i < 8; ++i) acc[i] = (f32x4){0.f, 0.f, 0.f, 0.f};

    float wgbuf[2][4];
    int   idxc[4];
    s16x8 G[2][16];
    float omv[2][3];
    int4  Wr[4];

#define SETUP(kq, wbuf, dyv, dxv, mv)                                          \
    {                                                                          \
        float py  = (float)(h + ((kq) / 3) - 1) + (dyv);                       \
        float pxf = (float)(w + ((kq) % 3) - 1) + (dxv);                       \
        float y0f = floorf(py), x0f = floorf(pxf);                             \
        float ly = py - y0f, lx = pxf - x0f;                                   \
        int y0 = (int)y0f, x0 = (int)x0f;                                      \
        _Pragma("unroll")                                                      \
        for (int cr = 0; cr < 4; ++cr) {                                       \
            int iy = y0 + (cr >> 1), ix = x0 + (cr & 1);                       \
            bool ok = ((unsigned)iy < (unsigned)Hh) && ((unsigned)ix < (unsigned)Ww); \
            float wy = (cr >> 1) ? ly : (1.f - ly);                            \
            float wx = (cr & 1) ? lx : (1.f - lx);                             \
            int cy = min(max(iy, 0), Hh - 1);                                  \
            int cx = min(max(ix, 0), Ww - 1);                                  \
            idxc[cr] = cy * Ww + cx;                                           \
            wgbuf[wbuf][cr] = ok ? (wy * wx * (mv)) : 0.f;                     \
        }                                                                      \
    }

#define ISSUEG(gbuf)                                                           \
    {                                                                          \
        _Pragma("unroll")                                                      \
        for (int cr = 0; cr < 4; ++cr) {                                       \
            const short* src = xbase + (size_t)idxc[cr] * Cc;                  \
            _Pragma("unroll")                                                  \
            for (int kk = 0; kk < 4; ++kk)                                     \
                G[gbuf][cr * 4 + kk] = *(const s16x8*)(src + kk * 32);         \
        }                                                                      \
    }

#define LOADOM(kq, obuf)                                                       \
    {                                                                          \
        size_t ob = (size_t)(b * 9 + (kq)) * HW + p;                           \
        omv[obuf][0] = dy_i[ob]; omv[obuf][1] = dx_i[ob]; omv[obuf][2] = mk_i[ob]; \
    }

#define LOADW(kq)                                                              \
    {                                                                          \
        const int4* src = (const int4*)(wb + (size_t)(kq) * 128 * 128);        \
        _Pragma("unroll")                                                      \
        for (int i2 = 0; i2 < 4; ++i2) Wr[i2] = src[i2 * 512 + t];             \
    }

#define WRITEW(bufIdx)                                                         \
    {                                                                          \
        _Pragma("unroll")                                                      \
        for (int i2 = 0; i2 < 4; ++i2) {                                       \
            int ci = i2 * 512 + t;                                             \
            int o = ci >> 4;                                                   \
            int byte = (ci << 4) ^ ((o & 15) << 4);                            \
            *(int4*)((char*)w_lds[bufIdx] + byte) = Wr[i2];                    \
        }                                                                      \
    }

    // ---- prologue ----
    LOADW(0);
    LOADOM(0, 0);
    LOADOM(1, 1);
    SETUP(0, 0, omv[0][0], omv[0][1], omv[0][2]);
    ISSUEG(0);
    WRITEW(0);
    __syncthreads();

#pragma unroll
    for (int k = 0; k < Kk; ++k) {
        // ---- top-of-iter issues: land before this iteration's barrier ----
        if (k < Kk - 1) LOADW(k + 1);
        if (k < Kk - 2) LOADOM(k + 2, k & 1);     // omv[k&1] consumed at SETUP(k)
        if (k < Kk - 1) {
            SETUP(k + 1, (k + 1) & 1,
                  omv[(k + 1) & 1][0], omv[(k + 1) & 1][1], omv[(k + 1) & 1][2]);
            ISSUEG((k + 1) & 1);
        }

        // ---- blend(k): consumes G[k&1], wgbuf[k&1] (landed last iteration) ----
        s16x8 afr[4];
#pragma unroll
        for (int kk = 0; kk < 4; ++kk) {
#pragma unroll
            for (int j = 0; j < 8; ++j) {
                float sv = wgbuf[k & 1][0] * bf2f(G[k & 1][0 * 4 + kk][j])
                         + wgbuf[k & 1][1] * bf2f(G[k & 1][1 * 4 + kk][j])
                         + wgbuf[k & 1][2] * bf2f(G[k & 1][2 * 4 + kk][j])
                         + wgbuf[k & 1][3] * bf2f(G[k & 1][3 * 4 + kk][j]);
                afr[kk][j] = f2bf(sv);
            }
        }

        // ---- MFMA(k): A in regs, B from w_lds[k&1] ----
        {
            const int orow = lane & 15;
#pragma unroll
            for (int ot = 0; ot < 8; ++ot) {
                int o = ot * 16 + orow;
#pragma unroll
                for (int kk = 0; kk < 4; ++kk) {
                    int byte = (o * 256 + (kk * 32 + kb8) * 2) ^ ((o & 15) << 4);
                    s16x8 bfr = *(const s16x8*)((char*)w_lds[k & 1] + byte);
                    acc[ot] = __builtin_amdgcn_mfma_f32_16x16x32_bf16(afr[kk], bfr, acc[ot], 0, 0, 0);
                }
            }
        }

        // ---- write next tap's weights (Wr long landed) ----
        if (k < Kk - 1) WRITEW((k + 1) & 1);
        __syncthreads();
    }

#undef SETUP
#undef ISSUEG
#undef LOADOM
#undef LOADW
#undef WRITEW

    // ---- epilogue ----
#pragma unroll
    for (int ot = 0; ot < 8; ++ot) {
        int o = ot * 16 + (lane & 15);
        float bo = bias[o];
        float4 r;
        r.x = acc[ot][0] + bo;
        r.y = acc[ot][1] + bo;
        r.z = acc[ot][2] + bo;
        r.w = acc[ot][3] + bo;
        *(float4*)(out + ((size_t)(b * On + o)) * HW + h * Ww + w0 + (lane >> 4) * 4) = r;
    }
}

// ---------------------------------------------------------------------------
extern "C" void kernel_launch(void* const* d_in, const int* in_sizes, int n_in,
                              void* d_out, int out_size, void* d_ws, size_t ws_size,
                              hipStream_t stream) {
    const float* x      = (const float*)d_in[0];
    const float* w_off  = (const float*)d_in[1];
    const float* b_off  = (const float*)d_in[2];
    const float* w_mask = (const float*)d_in[3];
    const float* b_mask = (const float*)d_in[4];
    const float* wt     = (const float*)d_in[5];
    const float* bias   = (const float*)d_in[6];
    float* out = (float*)d_out;

    short* xT  = (short*)d_ws;                      // B*HW*C bf16 hi
    short* xLo = xT + (size_t)Bn * HW * Cc;         // B*HW*C bf16 lo
    short* wb  = xLo + (size_t)Bn * HW * Cc;        // K*O*C bf16
    short* wofm_h = wb + Kk * On * Cc;
    short* wofm_l = wofm_h + Kk * 32 * Cc;
    float* dy = (float*)(wofm_l + Kk * 32 * Cc);
    float* dx = dy + (size_t)Bn * 9 * HW;
    float* mk = dx + (size_t)Bn * 9 * HW;

    to_nhwc<<<dim3(HW / 64, Bn), 256, 0, stream>>>(x, xT, xLo);
    prep_w<<<(Kk * On * Cc + 255) / 256, 256, 0, stream>>>(wt, wb);
    prep_wofm<<<(Kk * 32 * Cc + 255) / 256, 256, 0, stream>>>(w_off, w_mask, wofm_h, wofm_l);
    offmask_mfma<<<1600, 256, 0, stream>>>(
        xT, xLo, wofm_h, wofm_l, b_off, b_mask, dy, dx, mk);
    dconv_main<<<800, 512, 0, stream>>>(
        xT, wb, bias, dy, dx, mk, out);
}

// Round 19
// 301.896 us; speedup vs baseline: 1.8773x; 1.1140x over previous
//
#include <hip/hip_runtime.h>
#include <math.h>

constexpr int Bn = 4, Cc = 128, On = 128, Hh = 160, Ww = 160, Kk = 9;
constexpr int HW = Hh * Ww;          // 25600

typedef __attribute__((ext_vector_type(8))) short s16x8;
typedef __attribute__((ext_vector_type(4))) float f32x4;

__device__ inline float bf2f(short s) {
    union { float f; unsigned u; } v;
    v.u = ((unsigned)(unsigned short)s) << 16;
    return v.f;
}
__device__ inline short f2bf(float f) {
    union { float f; unsigned u; } v;
    v.f = f;
    unsigned r = v.u + 0x7fffu + ((v.u >> 16) & 1u);   // RNE
    return (short)(r >> 16);
}

// ---------------------------------------------------------------------------
// Kernel A1: x (NCHW f32) -> xT (NHWC bf16 hi) + xLo (NHWC bf16 lo).
// ---------------------------------------------------------------------------
__global__ __launch_bounds__(256) void to_nhwc(const float* __restrict__ x,
                                               short* __restrict__ xT,
                                               short* __restrict__ xLo) {
    __shared__ float tile[128][65];
    const int t = threadIdx.x;
    const int p0 = blockIdx.x * 64;
    const int b = blockIdx.y;
#pragma unroll
    for (int i = 0; i < 32; ++i) {
        int c = i * 4 + (t >> 6);
        tile[c][t & 63] = x[((size_t)b * Cc + c) * HW + p0 + (t & 63)];
    }
    __syncthreads();
    const int px = t >> 2, cq = t & 3;
    short* dsth = xT  + ((size_t)(b * HW) + p0 + px) * Cc;
    short* dstl = xLo + ((size_t)(b * HW) + p0 + px) * Cc;
#pragma unroll
    for (int j = 0; j < 8; ++j) {
        int c0 = cq * 4 + j * 16;
        short4 vh, vl;
        float f0 = tile[c0 + 0][px], f1 = tile[c0 + 1][px];
        float f2 = tile[c0 + 2][px], f3 = tile[c0 + 3][px];
        vh.x = f2bf(f0); vh.y = f2bf(f1); vh.z = f2bf(f2); vh.w = f2bf(f3);
        vl.x = f2bf(f0 - bf2f(vh.x));
        vl.y = f2bf(f1 - bf2f(vh.y));
        vl.z = f2bf(f2 - bf2f(vh.z));
        vl.w = f2bf(f3 - bf2f(vh.w));
        *(short4*)(dsth + c0) = vh;
        *(short4*)(dstl + c0) = vl;
    }
}

// ---------------------------------------------------------------------------
// Kernel A2: wt (O,C,3,3) f32 -> wb[k][o][c] bf16
// ---------------------------------------------------------------------------
__global__ void prep_w(const float* __restrict__ wt, short* __restrict__ wb) {
    int idx = blockIdx.x * 256 + threadIdx.x;     // K*O*C = 147456
    if (idx >= Kk * On * Cc) return;
    int c = idx & 127;
    int o = (idx >> 7) & 127;
    int k = idx >> 14;
    wb[idx] = f2bf(wt[(o * Cc + c) * 9 + k]);
}

// ---------------------------------------------------------------------------
// Kernel A3: offset/mask weights -> wofm_{hi,lo}[k][ch32][c].
// ---------------------------------------------------------------------------
__global__ void prep_wofm(const float* __restrict__ w_off,
                          const float* __restrict__ w_mask,
                          short* __restrict__ wh, short* __restrict__ wl) {
    int idx = blockIdx.x * 256 + threadIdx.x;     // 9*32*128 = 36864
    if (idx >= Kk * 32 * Cc) return;
    int c = idx & 127;
    int ch = (idx >> 7) & 31;
    int k = idx >> 12;
    float v = 0.f;
    if (ch < 18)      v = w_off[(ch * Cc + c) * 9 + k];
    else if (ch < 27) v = w_mask[((ch - 18) * Cc + c) * 9 + k];
    short hi = f2bf(v);
    wh[idx] = hi;
    wl[idx] = f2bf(v - bf2f(hi));
}

// ---------------------------------------------------------------------------
// Kernel B: offset/mask conv via MFMA, hi/lo split (r8/r13 version).
// ---------------------------------------------------------------------------
__global__ __launch_bounds__(256) void offmask_mfma(
    const short* __restrict__ xT, const short* __restrict__ xLo,
    const short* __restrict__ wh, const short* __restrict__ wl,
    const float* __restrict__ b_off, const float* __restrict__ b_mask,
    float* __restrict__ dy_o, float* __restrict__ dx_o, float* __restrict__ mk_o)
{
    __shared__ short a_hi[6][2304];
    __shared__ short a_lo[6][2304];

    const int g = blockIdx.x;
    const int orig = (g & 7) * 200 + (g >> 3);
    const int b  = orig / 400;
    const int rem = orig % 400;
    const int h0 = (rem / 10) * 4;
    const int w0 = (rem % 10) * 16;

    const int t = threadIdx.x;

    const short* xh_b = xT  + (size_t)b * HW * Cc;
    const short* xl_b = xLo + (size_t)b * HW * Cc;
#pragma unroll
    for (int j = 0; j < 14; ++j) {
        int ci = j * 256 + t;
        if (ci < 3456) {
            int slot = ci / 576;
            int rem2 = ci % 576;
            int isLo = rem2 >= 288;
            int cj   = isLo ? rem2 - 288 : rem2;
            int pxl  = cj >> 4;
            int ck   = cj & 15;
            int r   = h0 - 1 + slot;
            int col = w0 - 1 + pxl;
            int4 v = make_int4(0, 0, 0, 0);
            if ((unsigned)r < (unsigned)Hh && (unsigned)col < (unsigned)Ww) {
                const short* src = (isLo ? xl_b : xh_b) +
                                   ((size_t)(r * Ww + col)) * Cc + ck * 8;
                v = *(const int4*)src;
            }
            int byte = (pxl * 256 + ck * 16) ^ ((pxl & 7) << 4);
            *(int4*)((char*)(isLo ? a_lo[slot] : a_hi[slot]) + byte) = v;
        }
    }
    __syncthreads();

    const int lane = t & 63, wid = t >> 6;
    const int i  = lane & 15;
    const int kb = (lane >> 4) * 8;

    f32x4 acc[2];
    acc[0] = (f32x4){0.f, 0.f, 0.f, 0.f};
    acc[1] = (f32x4){0.f, 0.f, 0.f, 0.f};

    s16x8 bh[2][2][4], bl[2][2][4];

#pragma unroll
    for (int tile = 0; tile < 2; ++tile) {
        const short* bp = wh + ((size_t)(tile * 16 + i)) * Cc + kb;
        const short* lp = wl + ((size_t)(tile * 16 + i)) * Cc + kb;
#pragma unroll
        for (int kk = 0; kk < 4; ++kk) {
            bh[0][tile][kk] = *(const s16x8*)(bp + kk * 32);
            bl[0][tile][kk] = *(const s16x8*)(lp + kk * 32);
        }
    }

#pragma unroll
    for (int k = 0; k < Kk; ++k) {
        const int cur = k & 1, nxt = cur ^ 1;
        if (k < Kk - 1) {
            const int kn = k + 1;
#pragma unroll
            for (int tile = 0; tile < 2; ++tile) {
                const short* bp = wh + ((size_t)(kn * 32 + tile * 16 + i)) * Cc + kb;
                const short* lp = wl + ((size_t)(kn * 32 + tile * 16 + i)) * Cc + kb;
#pragma unroll
                for (int kk = 0; kk < 4; ++kk) {
                    bh[nxt][tile][kk] = *(const s16x8*)(bp + kk * 32);
                    bl[nxt][tile][kk] = *(const s16x8*)(lp + kk * 32);
                }
            }
        }
        const int ky = k / 3, kxi = k % 3;
        const int slot = wid + ky;
        const int pxl = i + kxi;
        s16x8 ah[4], al[4];
#pragma unroll
        for (int kk = 0; kk < 4; ++kk) {
            int byte = (pxl * 256 + (kk * 32 + kb) * 2) ^ ((pxl & 7) << 4);
            ah[kk] = *(const s16x8*)((char*)a_hi[slot] + byte);
            al[kk] = *(const s16x8*)((char*)a_lo[slot] + byte);
        }
#pragma unroll
        for (int tile = 0; tile < 2; ++tile) {
#pragma unroll
            for (int kk = 0; kk < 4; ++kk) {
                acc[tile] = __builtin_amdgcn_mfma_f32_16x16x32_bf16(ah[kk], bh[cur][tile][kk], acc[tile], 0, 0, 0);
                acc[tile] = __builtin_amdgcn_mfma_f32_16x16x32_bf16(al[kk], bh[cur][tile][kk], acc[tile], 0, 0, 0);
                acc[tile] = __builtin_amdgcn_mfma_f32_16x16x32_bf16(ah[kk], bl[cur][tile][kk], acc[tile], 0, 0, 0);
            }
        }
    }

    const int hr = h0 + wid;
#pragma unroll
    for (int tile = 0; tile < 2; ++tile) {
        int ch = tile * 16 + i;
#pragma unroll
        for (int reg = 0; reg < 4; ++reg) {
            int pxo = (lane >> 4) * 4 + reg;
            int p = hr * Ww + w0 + pxo;
            float v = acc[tile][reg];
            if (ch < 18) {
                int k = ch >> 1;
                v += b_off[ch];
                if (ch & 1) dx_o[(size_t)(b * 9 + k) * HW + p] = v;
                else        dy_o[(size_t)(b * 9 + k) * HW + p] = v;
            } else if (ch < 27) {
                int k = ch - 18;
                v += b_mask[k];
                mk_o[(size_t)(b * 9 + k) * HW + p] = 1.f / (1.f + expf(-v));
            }
        }
    }
}

// ---------------------------------------------------------------------------
// Kernel C: main deformable conv (r13 version — best verified: 151 us).
// 2-D pixel tiles (4 rows x 16 cols), double-buffered w_lds, 2-deep
// prefetch structure, XCD-chunked swizzle, 1 barrier per k.
// ---------------------------------------------------------------------------
__global__ __launch_bounds__(256) void dconv_main(
    const short* __restrict__ xT,    // [b][hw][c] bf16
    const short* __restrict__ wb,    // [k][o][c] bf16
    const float* __restrict__ bias,
    const float* __restrict__ dy_i, const float* __restrict__ dx_i,
    const float* __restrict__ mk_i,
    float* __restrict__ out)
{
    __shared__ short w_lds[2][128 * 128];   // 2 x 32 KB, byte ^= (o&15)<<4

    const int g = blockIdx.x;
    const int orig = (g & 7) * 200 + (g >> 3);
    const int b = orig / 400;
    const int rem = orig % 400;
    const int h0 = (rem / 10) * 4;
    const int w0 = (rem % 10) * 16;

    const int t = threadIdx.x;
    const int lane = t & 63;
    const int wid = t >> 6;

    const int i16 = lane & 15;
    const int h = h0 + wid;
    const int w = w0 + i16;
    const int p = h * Ww + w;
    const int kb8 = (lane >> 4) * 8;

    const short* xbase = xT + (size_t)b * HW * Cc + kb8;

    f32x4 acc[8];
#pragma unroll
    for (int i = 0; i < 8; ++i) acc[i] = (f32x4){0.f, 0.f, 0.f, 0.f};

    float wgbuf[2][4];
    int   idxc[4];
    s16x8 G[2][16];
    float omv[2][3];
    int4  Wr[8];

#define SETUP(kq, wbuf, dyv, dxv, mv)                                          \
    {                                                                          \
        float py  = (float)(h + ((kq) / 3) - 1) + (dyv);                       \
        float pxf = (float)(w + ((kq) % 3) - 1) + (dxv);                       \
        float y0f = floorf(py), x0f = floorf(pxf);                             \
        float ly = py - y0f, lx = pxf - x0f;                                   \
        int y0 = (int)y0f, x0 = (int)x0f;                                      \
        _Pragma("unroll")                                                      \
        for (int cr = 0; cr < 4; ++cr) {                                       \
            int iy = y0 + (cr >> 1), ix = x0 + (cr & 1);                       \
            bool ok = ((unsigned)iy < (unsigned)Hh) && ((unsigned)ix < (unsigned)Ww); \
            float wy = (cr >> 1) ? ly : (1.f - ly);                            \
            float wx = (cr & 1) ? lx : (1.f - lx);                             \
            int cy = min(max(iy, 0), Hh - 1);                                  \
            int cx = min(max(ix, 0), Ww - 1);                                  \
            idxc[cr] = cy * Ww + cx;                                           \
            wgbuf[wbuf][cr] = ok ? (wy * wx * (mv)) : 0.f;                     \
        }                                                                      \
    }

#define ISSUEG(gbuf)                                                           \
    {                                                                          \
        _Pragma("unroll")                                                      \
        for (int cr = 0; cr < 4; ++cr) {                                       \
            const short* src = xbase + (size_t)idxc[cr] * Cc;                  \
            _Pragma("unroll")                                                  \
            for (int kk = 0; kk < 4; ++kk)                                     \
                G[gbuf][cr * 4 + kk] = *(const s16x8*)(src + kk * 32);         \
        }                                                                      \
    }

#define LOADOM(kq, obuf)                                                       \
    {                                                                          \
        size_t ob = (size_t)(b * 9 + (kq)) * HW + p;                           \
        omv[obuf][0] = dy_i[ob]; omv[obuf][1] = dx_i[ob]; omv[obuf][2] = mk_i[ob]; \
    }

#define LOADW(kq)                                                              \
    {                                                                          \
        const int4* src = (const int4*)(wb + (size_t)(kq) * 128 * 128);        \
        _Pragma("unroll")                                                      \
        for (int i2 = 0; i2 < 8; ++i2) Wr[i2] = src[i2 * 256 + t];             \
    }

#define WRITEW(bufIdx)                                                         \
    {                                                                          \
        _Pragma("unroll")                                                      \
        for (int i2 = 0; i2 < 8; ++i2) {                                       \
            int ci = i2 * 256 + t;                                             \
            int o = ci >> 4;                                                   \
            int byte = (ci << 4) ^ ((o & 15) << 4);                            \
            *(int4*)((char*)w_lds[bufIdx] + byte) = Wr[i2];                    \
        }                                                                      \
    }

    // ---- prologue ----
    LOADW(0);
    LOADOM(0, 0);
    LOADOM(1, 1);
    SETUP(0, 0, omv[0][0], omv[0][1], omv[0][2]);
    ISSUEG(0);
    WRITEW(0);
    __syncthreads();

#pragma unroll
    for (int k = 0; k < Kk; ++k) {
        if (k < Kk - 1) LOADW(k + 1);
        if (k < Kk - 2) LOADOM(k + 2, k & 1);
        if (k < Kk - 1) {
            SETUP(k + 1, (k + 1) & 1,
                  omv[(k + 1) & 1][0], omv[(k + 1) & 1][1], omv[(k + 1) & 1][2]);
            ISSUEG((k + 1) & 1);
        }

        // ---- blend(k): consumes G[k&1], wgbuf[k&1] ----
        s16x8 afr[4];
#pragma unroll
        for (int kk = 0; kk < 4; ++kk) {
#pragma unroll
            for (int j = 0; j < 8; ++j) {
                float sv = wgbuf[k & 1][0] * bf2f(G[k & 1][0 * 4 + kk][j])
                         + wgbuf[k & 1][1] * bf2f(G[k & 1][1 * 4 + kk][j])
                         + wgbuf[k & 1][2] * bf2f(G[k & 1][2 * 4 + kk][j])
                         + wgbuf[k & 1][3] * bf2f(G[k & 1][3 * 4 + kk][j]);
                afr[kk][j] = f2bf(sv);
            }
        }

        // ---- MFMA(k): A in regs, B from w_lds[k&1] ----
        {
            const int orow = lane & 15;
#pragma unroll
            for (int ot = 0; ot < 8; ++ot) {
                int o = ot * 16 + orow;
#pragma unroll
                for (int kk = 0; kk < 4; ++kk) {
                    int byte = (o * 256 + (kk * 32 + kb8) * 2) ^ ((o & 15) << 4);
                    s16x8 bfr = *(const s16x8*)((char*)w_lds[k & 1] + byte);
                    acc[ot] = __builtin_amdgcn_mfma_f32_16x16x32_bf16(afr[kk], bfr, acc[ot], 0, 0, 0);
                }
            }
        }

        if (k < Kk - 1) WRITEW((k + 1) & 1);
        __syncthreads();
    }

#undef SETUP
#undef ISSUEG
#undef LOADOM
#undef LOADW
#undef WRITEW

    // ---- epilogue: D col=lane&15 (o), row=(lane>>4)*4+reg (px) ----
#pragma unroll
    for (int ot = 0; ot < 8; ++ot) {
        int o = ot * 16 + (lane & 15);
        float bo = bias[o];
        float4 r;
        r.x = acc[ot][0] + bo;
        r.y = acc[ot][1] + bo;
        r.z = acc[ot][2] + bo;
        r.w = acc[ot][3] + bo;
        *(float4*)(out + ((size_t)(b * On + o)) * HW + h * Ww + w0 + (lane >> 4) * 4) = r;
    }
}

// ---------------------------------------------------------------------------
extern "C" void kernel_launch(void* const* d_in, const int* in_sizes, int n_in,
                              void* d_out, int out_size, void* d_ws, size_t ws_size,
                              hipStream_t stream) {
    const float* x      = (const float*)d_in[0];
    const float* w_off  = (const float*)d_in[1];
    const float* b_off  = (const float*)d_in[2];
    const float* w_mask = (const float*)d_in[3];
    const float* b_mask = (const float*)d_in[4];
    const float* wt     = (const float*)d_in[5];
    const float* bias   = (const float*)d_in[6];
    float* out = (float*)d_out;

    short* xT  = (short*)d_ws;                      // B*HW*C bf16 hi
    short* xLo = xT + (size_t)Bn * HW * Cc;         // B*HW*C bf16 lo
    short* wb  = xLo + (size_t)Bn * HW * Cc;        // K*O*C bf16
    short* wofm_h = wb + Kk * On * Cc;
    short* wofm_l = wofm_h + Kk * 32 * Cc;
    float* dy = (float*)(wofm_l + Kk * 32 * Cc);
    float* dx = dy + (size_t)Bn * 9 * HW;
    float* mk = dx + (size_t)Bn * 9 * HW;

    to_nhwc<<<dim3(HW / 64, Bn), 256, 0, stream>>>(x, xT, xLo);
    prep_w<<<(Kk * On * Cc + 255) / 256, 256, 0, stream>>>(wt, wb);
    prep_wofm<<<(Kk * 32 * Cc + 255) / 256, 256, 0, stream>>>(w_off, w_mask, wofm_h, wofm_l);
    offmask_mfma<<<1600, 256, 0, stream>>>(
        xT, xLo, wofm_h, wofm_l, b_off, b_mask, dy, dx, mk);
    dconv_main<<<1600, 256, 0, stream>>>(
        xT, wb, bias, dy, dx, mk, out);
}

// Round 20
// 259.813 us; speedup vs baseline: 2.1814x; 1.1620x over previous
//
#include <hip/hip_runtime.h>
#include <math.h>

constexpr int Bn = 4, Cc = 128, On = 128, Hh = 160, Ww = 160, Kk = 9;
constexpr int HW = Hh * Ww;          // 25600

typedef __attribute__((ext_vector_type(8))) short s16x8;
typedef __attribute__((ext_vector_type(4))) float f32x4;

__device__ inline float bf2f(short s) {
    union { float f; unsigned u; } v;
    v.u = ((unsigned)(unsigned short)s) << 16;
    return v.f;
}
__device__ inline short f2bf(float f) {
    union { float f; unsigned u; } v;
    v.f = f;
    unsigned r = v.u + 0x7fffu + ((v.u >> 16) & 1u);   // RNE
    return (short)(r >> 16);
}

// ---------------------------------------------------------------------------
// Kernel A1: x (NCHW f32) -> xT (NHWC bf16 hi) + xLo (NHWC bf16 lo).
// ---------------------------------------------------------------------------
__global__ __launch_bounds__(256) void to_nhwc(const float* __restrict__ x,
                                               short* __restrict__ xT,
                                               short* __restrict__ xLo) {
    __shared__ float tile[128][65];
    const int t = threadIdx.x;
    const int p0 = blockIdx.x * 64;
    const int b = blockIdx.y;
#pragma unroll
    for (int i = 0; i < 32; ++i) {
        int c = i * 4 + (t >> 6);
        tile[c][t & 63] = x[((size_t)b * Cc + c) * HW + p0 + (t & 63)];
    }
    __syncthreads();
    const int px = t >> 2, cq = t & 3;
    short* dsth = xT  + ((size_t)(b * HW) + p0 + px) * Cc;
    short* dstl = xLo + ((size_t)(b * HW) + p0 + px) * Cc;
#pragma unroll
    for (int j = 0; j < 8; ++j) {
        int c0 = cq * 4 + j * 16;
        short4 vh, vl;
        float f0 = tile[c0 + 0][px], f1 = tile[c0 + 1][px];
        float f2 = tile[c0 + 2][px], f3 = tile[c0 + 3][px];
        vh.x = f2bf(f0); vh.y = f2bf(f1); vh.z = f2bf(f2); vh.w = f2bf(f3);
        vl.x = f2bf(f0 - bf2f(vh.x));
        vl.y = f2bf(f1 - bf2f(vh.y));
        vl.z = f2bf(f2 - bf2f(vh.z));
        vl.w = f2bf(f3 - bf2f(vh.w));
        *(short4*)(dsth + c0) = vh;
        *(short4*)(dstl + c0) = vl;
    }
}

// ---------------------------------------------------------------------------
// Kernel A2: wt (O,C,3,3) f32 -> wb[k][o][c] bf16
// ---------------------------------------------------------------------------
__global__ void prep_w(const float* __restrict__ wt, short* __restrict__ wb) {
    int idx = blockIdx.x * 256 + threadIdx.x;     // K*O*C = 147456
    if (idx >= Kk * On * Cc) return;
    int c = idx & 127;
    int o = (idx >> 7) & 127;
    int k = idx >> 14;
    wb[idx] = f2bf(wt[(o * Cc + c) * 9 + k]);
}

// ---------------------------------------------------------------------------
// Kernel A3: offset/mask weights -> wofm_{hi,lo}[k][ch32][c].
// ---------------------------------------------------------------------------
__global__ void prep_wofm(const float* __restrict__ w_off,
                          const float* __restrict__ w_mask,
                          short* __restrict__ wh, short* __restrict__ wl) {
    int idx = blockIdx.x * 256 + threadIdx.x;     // 9*32*128 = 36864
    if (idx >= Kk * 32 * Cc) return;
    int c = idx & 127;
    int ch = (idx >> 7) & 31;
    int k = idx >> 12;
    float v = 0.f;
    if (ch < 18)      v = w_off[(ch * Cc + c) * 9 + k];
    else if (ch < 27) v = w_mask[((ch - 18) * Cc + c) * 9 + k];
    short hi = f2bf(v);
    wh[idx] = hi;
    wl[idx] = f2bf(v - bf2f(hi));
}

// ---------------------------------------------------------------------------
// Kernel B: offset/mask conv via MFMA, hi/lo split. ONE change vs r13:
// the per-tap B-weight tile (16 KB hi+lo) is staged in LDS once per BLOCK
// per tap (Wr regs at top of iter -> MFMA(k) -> barrier -> write -> barrier),
// instead of each of the 4 waves loading the identical tile from global.
// Cuts the block's scattered L2 line-requests for B by 4x. Read addresses
// use dconv's proven (ch&15)<<4 XOR swizzle (0 bank conflicts in r19).
// Values and MFMA order bit-identical to r13.
// ---------------------------------------------------------------------------
__global__ __launch_bounds__(256) void offmask_mfma(
    const short* __restrict__ xT, const short* __restrict__ xLo,
    const short* __restrict__ wh, const short* __restrict__ wl,
    const float* __restrict__ b_off, const float* __restrict__ b_mask,
    float* __restrict__ dy_o, float* __restrict__ dx_o, float* __restrict__ mk_o)
{
    __shared__ short a_hi[6][2304];   // 27.6 KB halo (hi)
    __shared__ short a_lo[6][2304];   // 27.6 KB halo (lo)
    __shared__ short w_s[2][4096];    // 16 KB: [hi/lo][ch*128+c], swizzled

    const int g = blockIdx.x;
    const int orig = (g & 7) * 200 + (g >> 3);
    const int b  = orig / 400;
    const int rem = orig % 400;
    const int h0 = (rem / 10) * 4;
    const int w0 = (rem % 10) * 16;

    const int t = threadIdx.x;

    int4 Wr[4];   // staging regs: chunks {hi: t, 256+t}, {lo: t, 256+t}

#define LOADWF(kq)                                                             \
    {                                                                          \
        const int4* sh = (const int4*)(wh + (size_t)(kq) * 32 * Cc);           \
        const int4* sl = (const int4*)(wl + (size_t)(kq) * 32 * Cc);           \
        Wr[0] = sh[t]; Wr[1] = sh[256 + t];                                    \
        Wr[2] = sl[t]; Wr[3] = sl[256 + t];                                    \
    }

#define WRITEWF                                                                \
    {                                                                          \
        _Pragma("unroll")                                                      \
        for (int j2 = 0; j2 < 2; ++j2) {                                       \
            int ci = j2 * 256 + t;                                             \
            int ch = ci >> 4;                                                  \
            int byte = (ci << 4) ^ ((ch & 15) << 4);                           \
            *(int4*)((char*)w_s[0] + byte) = Wr[j2];                           \
            *(int4*)((char*)w_s[1] + byte) = Wr[2 + j2];                       \
        }                                                                      \
    }

    // ---- issue tap-0 weights, then stage halo ----
    LOADWF(0);

    const short* xh_b = xT  + (size_t)b * HW * Cc;
    const short* xl_b = xLo + (size_t)b * HW * Cc;
#pragma unroll
    for (int j = 0; j < 14; ++j) {
        int ci = j * 256 + t;
        if (ci < 3456) {
            int slot = ci / 576;
            int rem2 = ci % 576;
            int isLo = rem2 >= 288;
            int cj   = isLo ? rem2 - 288 : rem2;
            int pxl  = cj >> 4;
            int ck   = cj & 15;
            int r   = h0 - 1 + slot;
            int col = w0 - 1 + pxl;
            int4 v = make_int4(0, 0, 0, 0);
            if ((unsigned)r < (unsigned)Hh && (unsigned)col < (unsigned)Ww) {
                const short* src = (isLo ? xl_b : xh_b) +
                                   ((size_t)(r * Ww + col)) * Cc + ck * 8;
                v = *(const int4*)src;
            }
            int byte = (pxl * 256 + ck * 16) ^ ((pxl & 7) << 4);
            *(int4*)((char*)(isLo ? a_lo[slot] : a_hi[slot]) + byte) = v;
        }
    }
    __syncthreads();    // halo ready (Wr also long since landed)
    WRITEWF;            // stage tap-0 weights
    __syncthreads();    // w_s(0) visible

    const int lane = t & 63, wid = t >> 6;
    const int i  = lane & 15;
    const int kb = (lane >> 4) * 8;

    f32x4 acc[2];
    acc[0] = (f32x4){0.f, 0.f, 0.f, 0.f};
    acc[1] = (f32x4){0.f, 0.f, 0.f, 0.f};

#pragma unroll
    for (int k = 0; k < Kk; ++k) {
        // ---- issue next tap's weight loads (land during A-reads + MFMA) ----
        if (k < Kk - 1) LOADWF(k + 1);

        // ---- A fragments from halo LDS ----
        const int ky = k / 3, kxi = k % 3;
        const int slot = wid + ky;
        const int pxl = i + kxi;
        s16x8 ah[4], al[4];
#pragma unroll
        for (int kk = 0; kk < 4; ++kk) {
            int byte = (pxl * 256 + (kk * 32 + kb) * 2) ^ ((pxl & 7) << 4);
            ah[kk] = *(const s16x8*)((char*)a_hi[slot] + byte);
            al[kk] = *(const s16x8*)((char*)a_lo[slot] + byte);
        }

        // ---- B fragments from w_s (swizzled), MFMA (r13 op order) ----
#pragma unroll
        for (int tile = 0; tile < 2; ++tile) {
            const int ch = tile * 16 + i;
            s16x8 bh[4], bl[4];
#pragma unroll
            for (int kk = 0; kk < 4; ++kk) {
                int byte = (ch * 256 + (kk * 32 + kb) * 2) ^ ((ch & 15) << 4);
                bh[kk] = *(const s16x8*)((char*)w_s[0] + byte);
                bl[kk] = *(const s16x8*)((char*)w_s[1] + byte);
            }
#pragma unroll
            for (int kk = 0; kk < 4; ++kk) {
                acc[tile] = __builtin_amdgcn_mfma_f32_16x16x32_bf16(ah[kk], bh[kk], acc[tile], 0, 0, 0);
                acc[tile] = __builtin_amdgcn_mfma_f32_16x16x32_bf16(al[kk], bh[kk], acc[tile], 0, 0, 0);
                acc[tile] = __builtin_amdgcn_mfma_f32_16x16x32_bf16(ah[kk], bl[kk], acc[tile], 0, 0, 0);
            }
        }

        // ---- rotate the single weight buffer ----
        if (k < Kk - 1) {
            __syncthreads();   // all waves' w_s reads of tap k done
            WRITEWF;           // Wr landed during MFMA
            __syncthreads();   // tap k+1 weights visible
        }
    }

#undef LOADWF
#undef WRITEWF

    const int hr = h0 + wid;
#pragma unroll
    for (int tile = 0; tile < 2; ++tile) {
        int ch = tile * 16 + i;
#pragma unroll
        for (int reg = 0; reg < 4; ++reg) {
            int pxo = (lane >> 4) * 4 + reg;
            int p = hr * Ww + w0 + pxo;
            float v = acc[tile][reg];
            if (ch < 18) {
                int k = ch >> 1;
                v += b_off[ch];
                if (ch & 1) dx_o[(size_t)(b * 9 + k) * HW + p] = v;
                else        dy_o[(size_t)(b * 9 + k) * HW + p] = v;
            } else if (ch < 27) {
                int k = ch - 18;
                v += b_mask[k];
                mk_o[(size_t)(b * 9 + k) * HW + p] = 1.f / (1.f + expf(-v));
            }
        }
    }
}

// ---------------------------------------------------------------------------
// Kernel C: main deformable conv (r13 version — best verified: 151 us).
// ---------------------------------------------------------------------------
__global__ __launch_bounds__(256) void dconv_main(
    const short* __restrict__ xT,    // [b][hw][c] bf16
    const short* __restrict__ wb,    // [k][o][c] bf16
    const float* __restrict__ bias,
    const float* __restrict__ dy_i, const float* __restrict__ dx_i,
    const float* __restrict__ mk_i,
    float* __restrict__ out)
{
    __shared__ short w_lds[2][128 * 128];   // 2 x 32 KB, byte ^= (o&15)<<4

    const int g = blockIdx.x;
    const int orig = (g & 7) * 200 + (g >> 3);
    const int b = orig / 400;
    const int rem = orig % 400;
    const int h0 = (rem / 10) * 4;
    const int w0 = (rem % 10) * 16;

    const int t = threadIdx.x;
    const int lane = t & 63;
    const int wid = t >> 6;

    const int i16 = lane & 15;
    const int h = h0 + wid;
    const int w = w0 + i16;
    const int p = h * Ww + w;
    const int kb8 = (lane >> 4) * 8;

    const short* xbase = xT + (size_t)b * HW * Cc + kb8;

    f32x4 acc[8];
#pragma unroll
    for (int i = 0; i < 8; ++i) acc[i] = (f32x4){0.f, 0.f, 0.f, 0.f};

    float wgbuf[2][4];
    int   idxc[4];
    s16x8 G[2][16];
    float omv[2][3];
    int4  Wr[8];

#define SETUP(kq, wbuf, dyv, dxv, mv)                                          \
    {                                                                          \
        float py  = (float)(h + ((kq) / 3) - 1) + (dyv);                       \
        float pxf = (float)(w + ((kq) % 3) - 1) + (dxv);                       \
        float y0f = floorf(py), x0f = floorf(pxf);                             \
        float ly = py - y0f, lx = pxf - x0f;                                   \
        int y0 = (int)y0f, x0 = (int)x0f;                                      \
        _Pragma("unroll")                                                      \
        for (int cr = 0; cr < 4; ++cr) {                                       \
            int iy = y0 + (cr >> 1), ix = x0 + (cr & 1);                       \
            bool ok = ((unsigned)iy < (unsigned)Hh) && ((unsigned)ix < (unsigned)Ww); \
            float wy = (cr >> 1) ? ly : (1.f - ly);                            \
            float wx = (cr & 1) ? lx : (1.f - lx);                             \
            int cy = min(max(iy, 0), Hh - 1);                                  \
            int cx = min(max(ix, 0), Ww - 1);                                  \
            idxc[cr] = cy * Ww + cx;                                           \
            wgbuf[wbuf][cr] = ok ? (wy * wx * (mv)) : 0.f;                     \
        }                                                                      \
    }

#define ISSUEG(gbuf)                                                           \
    {                                                                          \
        _Pragma("unroll")                                                      \
        for (int cr = 0; cr < 4; ++cr) {                                       \
            const short* src = xbase + (size_t)idxc[cr] * Cc;                  \
            _Pragma("unroll")                                                  \
            for (int kk = 0; kk < 4; ++kk)                                     \
                G[gbuf][cr * 4 + kk] = *(const s16x8*)(src + kk * 32);         \
        }                                                                      \
    }

#define LOADOM(kq, obuf)                                                       \
    {                                                                          \
        size_t ob = (size_t)(b * 9 + (kq)) * HW + p;                           \
        omv[obuf][0] = dy_i[ob]; omv[obuf][1] = dx_i[ob]; omv[obuf][2] = mk_i[ob]; \
    }

#define LOADW(kq)                                                              \
    {                                                                          \
        const int4* src = (const int4*)(wb + (size_t)(kq) * 128 * 128);        \
        _Pragma("unroll")                                                      \
        for (int i2 = 0; i2 < 8; ++i2) Wr[i2] = src[i2 * 256 + t];             \
    }

#define WRITEW(bufIdx)                                                         \
    {                                                                          \
        _Pragma("unroll")                                                      \
        for (int i2 = 0; i2 < 8; ++i2) {                                       \
            int ci = i2 * 256 + t;                                             \
            int o = ci >> 4;                                                   \
            int byte = (ci << 4) ^ ((o & 15) << 4);                            \
            *(int4*)((char*)w_lds[bufIdx] + byte) = Wr[i2];                    \
        }                                                                      \
    }

    // ---- prologue ----
    LOADW(0);
    LOADOM(0, 0);
    LOADOM(1, 1);
    SETUP(0, 0, omv[0][0], omv[0][1], omv[0][2]);
    ISSUEG(0);
    WRITEW(0);
    __syncthreads();

#pragma unroll
    for (int k = 0; k < Kk; ++k) {
        if (k < Kk - 1) LOADW(k + 1);
        if (k < Kk - 2) LOADOM(k + 2, k & 1);
        if (k < Kk - 1) {
            SETUP(k + 1, (k + 1) & 1,
                  omv[(k + 1) & 1][0], omv[(k + 1) & 1][1], omv[(k + 1) & 1][2]);
            ISSUEG((k + 1) & 1);
        }

        // ---- blend(k): consumes G[k&1], wgbuf[k&1] ----
        s16x8 afr[4];
#pragma unroll
        for (int kk = 0; kk < 4; ++kk) {
#pragma unroll
            for (int j = 0; j < 8; ++j) {
                float sv = wgbuf[k & 1][0] * bf2f(G[k & 1][0 * 4 + kk][j])
                         + wgbuf[k & 1][1] * bf2f(G[k & 1][1 * 4 + kk][j])
                         + wgbuf[k & 1][2] * bf2f(G[k & 1][2 * 4 + kk][j])
                         + wgbuf[k & 1][3] * bf2f(G[k & 1][3 * 4 + kk][j]);
                afr[kk][j] = f2bf(sv);
            }
        }

        // ---- MFMA(k): A in regs, B from w_lds[k&1] ----
        {
            const int orow = lane & 15;
#pragma unroll
            for (int ot = 0; ot < 8; ++ot) {
                int o = ot * 16 + orow;
#pragma unroll
                for (int kk = 0; kk < 4; ++kk) {
                    int byte = (o * 256 + (kk * 32 + kb8) * 2) ^ ((o & 15) << 4);
                    s16x8 bfr = *(const s16x8*)((char*)w_lds[k & 1] + byte);
                    acc[ot] = __builtin_amdgcn_mfma_f32_16x16x32_bf16(afr[kk], bfr, acc[ot], 0, 0, 0);
                }
            }
        }

        if (k < Kk - 1) WRITEW((k + 1) & 1);
        __syncthreads();
    }

#undef SETUP
#undef ISSUEG
#undef LOADOM
#undef LOADW
#undef WRITEW

    // ---- epilogue: D col=lane&15 (o), row=(lane>>4)*4+reg (px) ----
#pragma unroll
    for (int ot = 0; ot < 8; ++ot) {
        int o = ot * 16 + (lane & 15);
        float bo = bias[o];
        float4 r;
        r.x = acc[ot][0] + bo;
        r.y = acc[ot][1] + bo;
        r.z = acc[ot][2] + bo;
        r.w = acc[ot][3] + bo;
        *(float4*)(out + ((size_t)(b * On + o)) * HW + h * Ww + w0 + (lane >> 4) * 4) = r;
    }
}

// ---------------------------------------------------------------------------
extern "C" void kernel_launch(void* const* d_in, const int* in_sizes, int n_in,
                              void* d_out, int out_size, void* d_ws, size_t ws_size,
                              hipStream_t stream) {
    const float* x      = (const float*)d_in[0];
    const float* w_off  = (const float*)d_in[1];
    const float* b_off  = (const float*)d_in[2];
    const float* w_mask = (const float*)d_in[3];
    const float* b_mask = (const float*)d_in[4];
    const float* wt     = (const float*)d_in[5];
    const float* bias   = (const float*)d_in[6];
    float* out = (float*)d_out;

    short* xT  = (short*)d_ws;                      // B*HW*C bf16 hi
    short* xLo = xT + (size_t)Bn * HW * Cc;         // B*HW*C bf16 lo
    short* wb  = xLo + (size_t)Bn * HW * Cc;        // K*O*C bf16
    short* wofm_h = wb + Kk * On * Cc;
    short* wofm_l = wofm_h + Kk * 32 * Cc;
    float* dy = (float*)(wofm_l + Kk * 32 * Cc);
    float* dx = dy + (size_t)Bn * 9 * HW;
    float* mk = dx + (size_t)Bn * 9 * HW;

    to_nhwc<<<dim3(HW / 64, Bn), 256, 0, stream>>>(x, xT, xLo);
    prep_w<<<(Kk * On * Cc + 255) / 256, 256, 0, stream>>>(wt, wb);
    prep_wofm<<<(Kk * 32 * Cc + 255) / 256, 256, 0, stream>>>(w_off, w_mask, wofm_h, wofm_l);
    offmask_mfma<<<1600, 256, 0, stream>>>(
        xT, xLo, wofm_h, wofm_l, b_off, b_mask, dy, dx, mk);
    dconv_main<<<1600, 256, 0, stream>>>(
        xT, wb, bias, dy, dx, mk, out);
}